// Round 5
// baseline (514.282 us; speedup 1.0000x reference)
//
#include <hip/hip_runtime.h>

typedef unsigned int u32;

// ---------------------------------------------------------------------------
// LiBNet forward, bit-packed ternary arithmetic + integer intermediates.
// dot over taps = popc(nzA & nzW) - 2*popc((sA ^ sW) & nzA & nzW)
// nz masks preserve sign(0)=0 semantics exactly (padding AND exact zeros).
// conv1 is computed twice (stats pass, then pool+pack pass) so the 134MB
// f32 activation tensor never exists.
// ---------------------------------------------------------------------------

static __device__ __forceinline__ float fsign(float x) {
    return (x > 0.f) ? 1.f : ((x < 0.f) ? -1.f : 0.f);
}
static __device__ __forceinline__ u32 pack4(int a, int b, int c, int d) {
    return (a & 0xff) | ((b & 0xff) << 8) | ((c & 0xff) << 16) | ((u32)(d & 0xff) << 24);
}

// --- merged weight prep: conv1 sign-f32, grouped packs, 1x1 packs ---
__global__ __launch_bounds__(256) void k_wprep(const float* __restrict__ w1, float* __restrict__ sw1f,
                                               const float* __restrict__ w2_1, u32* __restrict__ wpk21,
                                               const float* __restrict__ w3_1, u32* __restrict__ wpk31,
                                               const float* __restrict__ w2_2, u32* __restrict__ wp22,
                                               const float* __restrict__ w3_2, u32* __restrict__ wp32)
{
    int blk = blockIdx.x, tid = threadIdx.x;
    if (blk < 12) {
        int i = blk * 256 + tid;
        if (i < 3072) sw1f[i] = fsign(w1[i]);
        return;
    }
    if (blk == 12) {
        if (tid < 64) {   // grouped 4x4 weights, C=64
            const float* p = w2_1 + tid * 32;
            for (int r = 0; r < 8; ++r) {
                u32 sn = 0, nz = 0;
                for (int kw = 0; kw < 4; ++kw) {
                    float v = p[r * 4 + kw];
                    sn |= (u32)(v > 0.f) << kw;
                    nz |= (u32)(v != 0.f) << kw;
                }
                wpk21[tid * 8 + r] = sn | (nz << 8);
            }
        }
        {                 // 1x1 weights 256x64
            const float* p = w2_2 + (size_t)tid * 64;
            for (int j = 0; j < 2; ++j) {
                u32 sv = 0, nv = 0;
                for (int k = 0; k < 32; ++k) {
                    float v = p[j * 32 + k];
                    sv |= (u32)(v > 0.f) << k;
                    nv |= (u32)(v != 0.f) << k;
                }
                wp22[tid * 4 + j] = sv;
                wp22[tid * 4 + 2 + j] = nv;
            }
        }
        return;
    }
    {                     // blk == 13
        {                 // grouped 4x4 weights, C=256
            const float* p = w3_1 + tid * 32;
            for (int r = 0; r < 8; ++r) {
                u32 sn = 0, nz = 0;
                for (int kw = 0; kw < 4; ++kw) {
                    float v = p[r * 4 + kw];
                    sn |= (u32)(v > 0.f) << kw;
                    nz |= (u32)(v != 0.f) << kw;
                }
                wpk31[tid * 8 + r] = sn | (nz << 8);
            }
        }
        {                 // 1x1 weights 256x256
            const float* p = w3_2 + (size_t)tid * 256;
            for (int j = 0; j < 8; ++j) {
                u32 sv = 0, nv = 0;
                for (int k = 0; k < 32; ++k) {
                    float v = p[j * 32 + k];
                    sv |= (u32)(v > 0.f) << k;
                    nv |= (u32)(v != 0.f) << k;
                }
                wp32[tid * 16 + j] = sv;
                wp32[tid * 16 + 8 + j] = nv;
            }
        }
    }
}

// --- conv1 pass A: conv + per-channel sum/sumsq partials (no output tensor) ---
__global__ __launch_bounds__(256) void k_conv1s(const float* __restrict__ x,
                                                const float* __restrict__ swf,
                                                double* __restrict__ part)
{
    __shared__ float sx[3 * 35 * 35];
    __shared__ float sred[64 * 8];   // [oc][wave*2 + {sum,sq}]
    int b = blockIdx.x >> 2, q = blockIdx.x & 3;
    for (int i = threadIdx.x; i < 3 * 35 * 35; i += 256) sx[i] = 0.f;
    __syncthreads();
    const float* xb = x + (size_t)b * 3072;
    for (int i = threadIdx.x; i < 3072; i += 256) {
        int w = i & 31, h = (i >> 5) & 31, ic = i >> 10;
        sx[(ic * 35 + h + 1) * 35 + w + 1] = xb[i];
    }
    __syncthreads();
    int pos = q * 256 + threadIdx.x;
    int h = pos >> 5, w = pos & 31;
    int lane = threadIdx.x & 63, wv = threadIdx.x >> 6;
    float in[48];
#pragma unroll
    for (int ic = 0; ic < 3; ++ic)
#pragma unroll
        for (int kh = 0; kh < 4; ++kh)
#pragma unroll
            for (int kw = 0; kw < 4; ++kw)
                in[ic * 16 + kh * 4 + kw] = sx[(ic * 35 + h + kh) * 35 + w + kw];
#pragma unroll 4
    for (int oc = 0; oc < 64; ++oc) {
        const float* wp = swf + oc * 48;   // wave-uniform -> s_load
        float a0 = 0.f, a1 = 0.f, a2 = 0.f, a3 = 0.f;
#pragma unroll
        for (int k = 0; k < 48; k += 4) {
            a0 += in[k]     * wp[k];
            a1 += in[k + 1] * wp[k + 1];
            a2 += in[k + 2] * wp[k + 2];
            a3 += in[k + 3] * wp[k + 3];
        }
        float v = (a0 + a1) + (a2 + a3);
        float s = v, sq = v * v;
#pragma unroll
        for (int m = 1; m < 64; m <<= 1) {
            s  += __shfl_xor(s, m);
            sq += __shfl_xor(sq, m);
        }
        if (lane == 0) {
            sred[oc * 8 + 2 * wv]     = s;
            sred[oc * 8 + 2 * wv + 1] = sq;
        }
    }
    __syncthreads();
    if (threadIdx.x < 128) {
        int oc = threadIdx.x >> 1, half = threadIdx.x & 1;
        double acc = (double)sred[oc * 8 + 0 + half] + (double)sred[oc * 8 + 2 + half]
                   + (double)sred[oc * 8 + 4 + half] + (double)sred[oc * 8 + 6 + half];
        part[((size_t)oc * 2048 + blockIdx.x) * 2 + half] = acc;
    }
}

// --- conv1 pass B: conv + bn + 2x2 pool + binarize + row-bitpack ---
__global__ __launch_bounds__(256) void k_conv1p(const float* __restrict__ x,
                                                const float* __restrict__ swf,
                                                const float4* __restrict__ st,
                                                u32* __restrict__ spk,
                                                u32* __restrict__ npk)
{
    __shared__ float sx[3 * 35 * 35];
    int b = blockIdx.x >> 2, q = blockIdx.x & 3;
    for (int i = threadIdx.x; i < 3 * 35 * 35; i += 256) sx[i] = 0.f;
    __syncthreads();
    const float* xb = x + (size_t)b * 3072;
    for (int i = threadIdx.x; i < 3072; i += 256) {
        int w = i & 31, h = (i >> 5) & 31, ic = i >> 10;
        sx[(ic * 35 + h + 1) * 35 + w + 1] = xb[i];
    }
    __syncthreads();
    int pos = q * 256 + threadIdx.x;
    int h = pos >> 5, w = pos & 31;
    int lane = threadIdx.x & 63, wv = threadIdx.x >> 6;
    int oh = q * 4 + wv;                 // pooled row this wave produces
    float in[48];
#pragma unroll
    for (int ic = 0; ic < 3; ++ic)
#pragma unroll
        for (int kh = 0; kh < 4; ++kh)
#pragma unroll
            for (int kw = 0; kw < 4; ++kw)
                in[ic * 16 + kh * 4 + kw] = sx[(ic * 35 + h + kh) * 35 + w + kw];
#pragma unroll 4
    for (int oc = 0; oc < 64; ++oc) {
        const float* wp = swf + oc * 48;
        float a0 = 0.f, a1 = 0.f, a2 = 0.f, a3 = 0.f;
#pragma unroll
        for (int k = 0; k < 48; k += 4) {
            a0 += in[k]     * wp[k];
            a1 += in[k + 1] * wp[k + 1];
            a2 += in[k + 2] * wp[k + 2];
            a3 += in[k + 3] * wp[k + 3];
        }
        float v = (a0 + a1) + (a2 + a3);
        float4 s = st[oc];
        bool posi = (s.y > 0.f);
        // 2x2 pool: horizontal pair (xor 1), vertical pair (xor 32)
        float p1 = __shfl_xor(v, 1);
        float m1 = posi ? fmaxf(v, p1) : fminf(v, p1);
        float p2 = __shfl_xor(m1, 32);
        float m2 = posi ? fmaxf(m1, p2) : fminf(m1, p2);
        // gather pooled values (at even lanes <32) to lanes 0..15
        float pooled = __shfl(m2, 2 * (lane & 15));
        float bn = (pooled - s.x) * s.y + s.z;
        unsigned long long bs = __ballot(bn > 0.f);
        unsigned long long bnz = __ballot(bn != 0.f);
        if (lane == 0) {
            size_t base = (size_t)(b * 64 + oc) * 20;
            spk[base + 1 + oh] = (((u32)bs) & 0xffffu) << 1;
            npk[base + 1 + oh] = (((u32)bnz) & 0xffffu) << 1;
        }
    }
    // margin slots 0,17,18,19 zeroed once per image (quarter q==0)
    if (q == 0) {
        int c = threadIdx.x >> 2, m = threadIdx.x & 3;
        int zs = (m == 0) ? 0 : (16 + m);
        size_t base = (size_t)(b * 64 + c) * 20;
        spk[base + zs] = 0; npk[base + zs] = 0;
    }
}

// --- int8 stats: exact int32 block sums -> double partials ---
__global__ __launch_bounds__(256) void k_stats_i8(const signed char* __restrict__ in,
                                                  double* __restrict__ part,
                                                  int C, int HW, int bPerChunk)
{
    int c = blockIdx.x, chunk = blockIdx.y, b0 = chunk * bPerChunk;
    int q4 = HW >> 2;
    int s = 0, sq = 0;
    for (int b = b0; b < b0 + bPerChunk; ++b) {
        const u32* p = (const u32*)(in + (size_t)(b * C + c) * HW);
        for (int i = threadIdx.x; i < q4; i += 256) {
            u32 v = p[i];
            int x0 = (int)(v << 24) >> 24, x1 = (int)(v << 16) >> 24;
            int x2 = (int)(v << 8) >> 24,  x3 = (int)v >> 24;
            s += x0 + x1 + x2 + x3;
            sq += x0 * x0 + x1 * x1 + x2 * x2 + x3 * x3;
        }
    }
    __shared__ int ss[256];
    __shared__ int sb[256];
    ss[threadIdx.x] = s; sb[threadIdx.x] = sq;
    __syncthreads();
    for (int st = 128; st > 0; st >>= 1) {
        if (threadIdx.x < st) {
            ss[threadIdx.x] += ss[threadIdx.x + st];
            sb[threadIdx.x] += sb[threadIdx.x + st];
        }
        __syncthreads();
    }
    if (threadIdx.x == 0) {
        int nch = gridDim.y;
        part[(size_t)(c * nch + chunk) * 2]     = (double)ss[0];
        part[(size_t)(c * nch + chunk) * 2 + 1] = (double)sb[0];
    }
}

// --- int16 stats ---
__global__ __launch_bounds__(256) void k_stats_i16(const short* __restrict__ in,
                                                   double* __restrict__ part,
                                                   int C, int HW, int bPerChunk)
{
    int c = blockIdx.x, chunk = blockIdx.y, b0 = chunk * bPerChunk;
    int q2 = HW >> 1;
    int s = 0, sq = 0;
    for (int b = b0; b < b0 + bPerChunk; ++b) {
        const u32* p = (const u32*)(in + (size_t)(b * C + c) * HW);
        for (int i = threadIdx.x; i < q2; i += 256) {
            u32 v = p[i];
            int x0 = (int)(v << 16) >> 16, x1 = (int)v >> 16;
            s += x0 + x1;
            sq += x0 * x0 + x1 * x1;
        }
    }
    __shared__ int ss[256];
    __shared__ int sb[256];
    ss[threadIdx.x] = s; sb[threadIdx.x] = sq;
    __syncthreads();
    for (int st = 128; st > 0; st >>= 1) {
        if (threadIdx.x < st) {
            ss[threadIdx.x] += ss[threadIdx.x + st];
            sb[threadIdx.x] += sb[threadIdx.x + st];
        }
        __syncthreads();
    }
    if (threadIdx.x == 0) {
        int nch = gridDim.y;
        part[(size_t)(c * nch + chunk) * 2]     = (double)ss[0];
        part[(size_t)(c * nch + chunk) * 2 + 1] = (double)sb[0];
    }
}

// --- finalize: block per channel; mean/var -> power-of-two shift scale ---
__global__ __launch_bounds__(256) void k_finalize2(const double* __restrict__ part,
                                                   int nch, int N,
                                                   const float* __restrict__ gamma,
                                                   const float* __restrict__ beta,
                                                   float4* __restrict__ st)
{
    int c = blockIdx.x;
    double s = 0.0, sq = 0.0;
    for (int i = threadIdx.x; i < nch; i += 256) {
        s  += part[((size_t)c * nch + i) * 2];
        sq += part[((size_t)c * nch + i) * 2 + 1];
    }
    __shared__ double ss[256];
    __shared__ double sb[256];
    ss[threadIdx.x] = s; sb[threadIdx.x] = sq;
    __syncthreads();
    for (int stp = 128; stp > 0; stp >>= 1) {
        if (threadIdx.x < stp) {
            ss[threadIdx.x] += ss[threadIdx.x + stp];
            sb[threadIdx.x] += sb[threadIdx.x + stp];
        }
        __syncthreads();
    }
    if (threadIdx.x == 0) {
        double mean = ss[0] / (double)N;
        double var = sb[0] / (double)N - mean * mean;
        float inv = gamma[c] / sqrtf((float)var + 1e-5f);
        float sh = rintf(log2f(fabsf(inv) + 1e-12f));
        sh = fminf(fmaxf(sh, -4.f), 4.f);
        float scale = copysignf(exp2f(sh), inv);
        st[c] = make_float4((float)mean, scale, beta[c], 0.f);
    }
}

// --- layer2->3 bn+pool+pack: int8 in [512,256,16,16], wave per channel ---
__global__ __launch_bounds__(256) void k_poolpack3(const signed char* __restrict__ in,
                                                   const float4* __restrict__ st,
                                                   u32* __restrict__ spk,
                                                   u32* __restrict__ npk)
{
    int wv = threadIdx.x >> 6, lane = threadIdx.x & 63;
    int bc = blockIdx.x * 4 + wv;     // b*256 + c
    int c = bc & 255;
    int oh = lane >> 3, ow = lane & 7;
    float4 s = st[c];
    const signed char* p = in + (size_t)bc * 256 + (2 * oh) * 16 + 2 * ow;
    short s01 = *(const short*)p;
    short s23 = *(const short*)(p + 16);
    int a0 = (int)(signed char)(s01 & 0xff), a1 = (int)(s01 >> 8);
    int a2 = (int)(signed char)(s23 & 0xff), a3 = (int)(s23 >> 8);
    bool pos = (s.y > 0.f);
    int raw = pos ? max(max(a0, a1), max(a2, a3)) : min(min(a0, a1), min(a2, a3));
    float v = ((float)raw - s.x) * s.y + s.z;
    unsigned long long bs = __ballot(v > 0.f);
    unsigned long long bn = __ballot(v != 0.f);
    size_t base = (size_t)bc * 12;
    if (ow == 0) {
        spk[base + 1 + oh] = (((u32)(bs >> (8 * oh))) & 0xffu) << 1;
        npk[base + 1 + oh] = (((u32)(bn >> (8 * oh))) & 0xffu) << 1;
    }
    if (lane < 4) {                   // zero margin slots 0,9,10,11
        int zs = (lane == 0) ? 0 : (8 + lane);
        spk[base + zs] = 0; npk[base + zs] = 0;
    }
}

// --- grouped 4x4 binary conv, bit-packed in, int8 out. Thread=(b,group,row). ---
template <int C, int H>
__global__ __launch_bounds__(256) void k_convg_bp(const u32* __restrict__ spk,
                                                  const u32* __restrict__ npk,
                                                  const u32* __restrict__ wpk,
                                                  signed char* __restrict__ out)
{
    constexpr int SLOTS = (H == 16) ? 20 : 12;
    int t = blockIdx.x * 256 + threadIdx.x;
    int h = t % H; int r0 = t / H;
    int g = r0 % (C / 2); int b = r0 / (C / 2);
    const u32* sp = spk + (size_t)(b * C + 2 * g) * SLOTS + h;
    const u32* np = npk + (size_t)(b * C + 2 * g) * SLOTS + h;
    u32 S[8], N[8];
#pragma unroll
    for (int jc = 0; jc < 2; ++jc)
#pragma unroll
        for (int jj = 0; jj < 4; ++jj) {    // slot h+jj = input row h-1+jj
            S[jc * 4 + jj] = sp[jc * SLOTS + jj];
            N[jc * 4 + jj] = np[jc * SLOTS + jj];
        }
    const u32* wq = wpk + (size_t)(2 * g) * 8;
    u32 Ws0[8], Wn0[8], Ws1[8], Wn1[8];
#pragma unroll
    for (int r = 0; r < 8; ++r) {
        u32 a = wq[r];      Ws0[r] = a & 15u;  Wn0[r] = (a >> 8) & 15u;
        u32 bb = wq[8 + r]; Ws1[r] = bb & 15u; Wn1[r] = (bb >> 8) & 15u;
    }
    int v0[H], v1[H];
#pragma unroll
    for (int w = 0; w < H; ++w) {
        int snz0 = 0, smis0 = 0, snz1 = 0, smis1 = 0;
#pragma unroll
        for (int r = 0; r < 8; ++r) {
            u32 ss = (S[r] >> w) & 15u;
            u32 nn = (N[r] >> w) & 15u;
            u32 nz0 = nn & Wn0[r]; u32 m0 = (ss ^ Ws0[r]) & nz0;
            snz0 += __popc(nz0); smis0 += __popc(m0);
            u32 nz1 = nn & Wn1[r]; u32 m1 = (ss ^ Ws1[r]) & nz1;
            snz1 += __popc(nz1); smis1 += __popc(m1);
        }
        v0[w] = snz0 - 2 * smis0;
        v1[w] = snz1 - 2 * smis1;
    }
    signed char* o0 = out + ((size_t)((b * C + 2 * g) * H + h)) * H;
    signed char* o1 = o0 + (size_t)H * H;
    u32 wb0[H / 4], wb1[H / 4];
#pragma unroll
    for (int j = 0; j < H / 4; ++j) {
        wb0[j] = pack4(v0[4*j], v0[4*j+1], v0[4*j+2], v0[4*j+3]);
        wb1[j] = pack4(v1[4*j], v1[4*j+1], v1[4*j+2], v1[4*j+3]);
    }
    if constexpr (H == 16) {
        *(uint4*)o0 = make_uint4(wb0[0], wb0[1], wb0[2], wb0[3]);
        *(uint4*)o1 = make_uint4(wb1[0], wb1[1], wb1[2], wb1[3]);
    } else {
        *(uint2*)o0 = make_uint2(wb0[0], wb0[1]);
        *(uint2*)o1 = make_uint2(wb1[0], wb1[1]);
    }
}

// --- bn + binarize + channel-bitpack from int8: act[t] = {signs..., nz...} ---
template <int C, int HW>
__global__ __launch_bounds__(256) void k_bnpackC(const signed char* __restrict__ q,
                                                 const float4* __restrict__ st,
                                                 u32* __restrict__ act)
{
    constexpr int W = C / 32;
    int t = blockIdx.x * 256 + threadIdx.x;   // t = b*HW + hw
    int hw = t % HW; int b = t / HW;
    const signed char* qp = q + (size_t)b * C * HW + hw;
    u32* ap = act + (size_t)t * 2 * W;
#pragma unroll
    for (int j = 0; j < W; ++j) {
        u32 sv = 0, nv = 0;
#pragma unroll
        for (int k = 0; k < 32; ++k) {
            int c = j * 32 + k;
            float4 s = st[c];
            float v = ((float)qp[(size_t)c * HW] - s.x) * s.y + s.z;
            sv |= (u32)(v > 0.f) << k;
            nv |= (u32)(v != 0.f) << k;
        }
        ap[j] = sv; ap[W + j] = nv;
    }
}

// --- 1x1 conv, Cin=64, Cout=256, HW=256, int8 out. Thread=(b,hw). ---
__global__ __launch_bounds__(256) void k_conv1x1_bp2(const u32* __restrict__ act,
                                                     const u32* __restrict__ wp,
                                                     signed char* __restrict__ out)
{
    int t = blockIdx.x * 256 + threadIdx.x;   // t = b*256 + hw
    int hw = t & 255; int b = t >> 8;
    uint4 av = ((const uint4*)act)[t];        // s0,s1,n0,n1
    signed char* op = out + (size_t)b * 256 * 256 + hw;
#pragma unroll 8
    for (int oc = 0; oc < 256; ++oc) {
        uint4 wv = ((const uint4*)wp)[oc];    // wave-uniform -> scalar loads
        u32 nz0 = av.z & wv.z, nz1 = av.w & wv.w;
        u32 m0 = (av.x ^ wv.x) & nz0, m1 = (av.y ^ wv.y) & nz1;
        int dot = __popc(nz0) + __popc(nz1) - 2 * (__popc(m0) + __popc(m1));
        op[(size_t)oc << 8] = (signed char)dot;
    }
}

// --- 1x1 conv, Cin=256, Cout=256 (4 chunks), HW=64, int16 out. ---
__global__ __launch_bounds__(256) void k_conv1x1_bp3(const u32* __restrict__ act,
                                                     const u32* __restrict__ wp,
                                                     short* __restrict__ out)
{
    int t = blockIdx.x * 256 + threadIdx.x;
    int hw = t & 63; int ch = (t >> 6) & 3; int b = t >> 8;
    const u32* ap = act + (size_t)(b * 64 + hw) * 16;
    u32 as[8], an[8];
#pragma unroll
    for (int j = 0; j < 8; ++j) { as[j] = ap[j]; an[j] = ap[8 + j]; }
    short* op = out + (size_t)b * 256 * 64 + hw;
#pragma unroll 4
    for (int oc = ch * 64; oc < ch * 64 + 64; ++oc) {
        const u32* wq = wp + oc * 16;
        int snz = 0, smis = 0;
#pragma unroll
        for (int j = 0; j < 8; ++j) {
            u32 nz = an[j] & wq[8 + j];
            u32 m = (as[j] ^ wq[j]) & nz;
            snz += __popc(nz); smis += __popc(m);
        }
        op[(size_t)oc * 64] = (short)(snz - 2 * smis);
    }
}

// --- FC prep: fold bn3_2 into fc weights / bias ---
__global__ __launch_bounds__(256) void k_fcprep_w(const float* __restrict__ fcw,
                                                  const float4* __restrict__ st,
                                                  float* __restrict__ w2)
{
    int idx = blockIdx.x * 256 + threadIdx.x;   // < 163840
    int k = idx & 16383;
    w2[idx] = fcw[idx] * st[k >> 6].y;
}

__global__ __launch_bounds__(256) void k_fcprep_b(const float* __restrict__ fcw,
                                                  const float4* __restrict__ st,
                                                  const float* __restrict__ fcb,
                                                  float* __restrict__ bias2)
{
    int n = blockIdx.x;
    const float* p = fcw + (size_t)n * 16384;
    float acc = 0.f;
    for (int k = threadIdx.x; k < 16384; k += 256) {
        float4 s = st[k >> 6];
        acc += p[k] * (s.z - s.x * s.y);
    }
    __shared__ float ss[256];
    ss[threadIdx.x] = acc;
    __syncthreads();
    for (int stp = 128; stp > 0; stp >>= 1) {
        if (threadIdx.x < stp) ss[threadIdx.x] += ss[threadIdx.x + stp];
        __syncthreads();
    }
    if (threadIdx.x == 0) bias2[n] = ss[0] + fcb[n];
}

// --- FC: block per image, int16 features read once, 10 accumulators ---
__global__ __launch_bounds__(256) void k_fc2(const short* __restrict__ f,
                                             const float* __restrict__ w2,
                                             const float* __restrict__ bias2,
                                             float* __restrict__ out)
{
    int b = blockIdx.x, t = threadIdx.x;
    int lane = t & 63, wv = t >> 6;
    const u32* fp = (const u32*)(f + (size_t)b * 16384);
    float acc[10];
#pragma unroll
    for (int n = 0; n < 10; ++n) acc[n] = 0.f;
    for (int i = 0; i < 32; ++i) {
        int j = i * 256 + t;                 // u32 index; features 2j, 2j+1
        u32 v = fp[j];
        float f0 = (float)((int)(v << 16) >> 16);
        float f1 = (float)((int)v >> 16);
#pragma unroll
        for (int n = 0; n < 10; ++n) {
            float2 wv2 = *(const float2*)(w2 + (size_t)n * 16384 + 2 * j);
            acc[n] += f0 * wv2.x + f1 * wv2.y;
        }
    }
#pragma unroll
    for (int n = 0; n < 10; ++n)
#pragma unroll
        for (int m = 1; m < 64; m <<= 1) acc[n] += __shfl_xor(acc[n], m);
    __shared__ float sred[4][10];
    if (lane == 0)
#pragma unroll
        for (int n = 0; n < 10; ++n) sred[wv][n] = acc[n];
    __syncthreads();
    if (t < 10)
        out[b * 10 + t] = sred[0][t] + sred[1][t] + sred[2][t] + sred[3][t] + bias2[t];
}

extern "C" void kernel_launch(void* const* d_in, const int* in_sizes, int n_in,
                              void* d_out, int out_size, void* d_ws, size_t ws_size,
                              hipStream_t stream)
{
    const float* x    = (const float*)d_in[0];
    const float* w1   = (const float*)d_in[1];
    const float* g1   = (const float*)d_in[2];
    const float* b1   = (const float*)d_in[3];
    const float* w2_1 = (const float*)d_in[4];
    const float* g2_1 = (const float*)d_in[5];
    const float* b2_1 = (const float*)d_in[6];
    const float* w2_2 = (const float*)d_in[7];
    const float* g2_2 = (const float*)d_in[8];
    const float* b2_2 = (const float*)d_in[9];
    const float* w3_1 = (const float*)d_in[10];
    const float* g3_1 = (const float*)d_in[11];
    const float* b3_1 = (const float*)d_in[12];
    const float* w3_2 = (const float*)d_in[13];
    const float* g3_2 = (const float*)d_in[14];
    const float* b3_2 = (const float*)d_in[15];
    const float* fcw  = (const float*)d_in[16];
    const float* fcb  = (const float*)d_in[17];
    float* out = (float*)d_out;

    // workspace layout (bytes)
    const size_t OFF_C22  = 0;          // 33,554,432  conv2_2 int8 out
    const size_t OFF_F3   = 33554432;   // 16,777,216  conv3_2 int16 out
    const size_t OFF_Q    = 50331648;   //  8,388,608  convg int8 outs
    const size_t OFF_SPK2 = 58720256;   //  2,621,440  [512][64][20]
    const size_t OFF_NPK2 = 61341696;   //  2,621,440
    const size_t OFF_SPK3 = 63963136;   //  6,291,456  [512][256][12]
    const size_t OFF_NPK3 = 70254592;   //  6,291,456
    const size_t OFF_A    = 76546048;   //  2,097,152  packed acts
    const size_t OFF_WPK21= 78643200;   //  2,048
    const size_t OFF_WPK31= 78645248;   //  8,192
    const size_t OFF_WP22 = 78653440;   //  4,096
    const size_t OFF_WP32 = 78657536;   //  16,384
    const size_t OFF_PART = 78673920;   //  2,097,152  (64ch x 2048 chunks x 2 f64)
    const size_t OFF_ST   = 80771072;   //  20,480     5 x 256 float4
    const size_t OFF_SW1  = 80791552;   //  12,288     conv1 signed weights f32
    const size_t OFF_W2   = 80803840;   //  655,360    bn-folded fc weights
    const size_t OFF_B2   = 81459200;   //  256        bn-folded fc bias
    const size_t NEED     = OFF_B2 + 256;
    if (ws_size < NEED) return;

    char* ws = (char*)d_ws;
    signed char* c22 = (signed char*)(ws + OFF_C22);
    short* f3  = (short*)(ws + OFF_F3);
    signed char* q8 = (signed char*)(ws + OFF_Q);
    u32* spk2  = (u32*)(ws + OFF_SPK2);
    u32* npk2  = (u32*)(ws + OFF_NPK2);
    u32* spk3  = (u32*)(ws + OFF_SPK3);
    u32* npk3  = (u32*)(ws + OFF_NPK3);
    u32* actA  = (u32*)(ws + OFF_A);
    u32* wpk21 = (u32*)(ws + OFF_WPK21);
    u32* wpk31 = (u32*)(ws + OFF_WPK31);
    u32* wp22  = (u32*)(ws + OFF_WP22);
    u32* wp32  = (u32*)(ws + OFF_WP32);
    double* part = (double*)(ws + OFF_PART);
    float4* st1  = (float4*)(ws + OFF_ST);
    float4* st21 = st1 + 256;
    float4* st22 = st21 + 256;
    float4* st31 = st22 + 256;
    float4* st32 = st31 + 256;
    float* sw1f  = (float*)(ws + OFF_SW1);
    float* w2f   = (float*)(ws + OFF_W2);
    float* b2f   = (float*)(ws + OFF_B2);

    // ---- weight prep (all binarized weights, one launch) ----
    k_wprep<<<14, 256, 0, stream>>>(w1, sw1f, w2_1, wpk21, w3_1, wpk31, w2_2, wp22, w3_2, wp32);

    // ---- layer 1: conv1 twice (stats pass, then pool+pack pass) ----
    k_conv1s<<<2048, 256, 0, stream>>>(x, sw1f, part);
    k_finalize2<<<64, 256, 0, stream>>>(part, 2048, 512 * 1024, g1, b1, st1);
    k_conv1p<<<2048, 256, 0, stream>>>(x, sw1f, st1, spk2, npk2);   // packed 16x16

    // ---- layer 2 ----
    k_convg_bp<64, 16><<<1024, 256, 0, stream>>>(spk2, npk2, wpk21, q8); // [512,64,16,16] i8
    k_stats_i8<<<dim3(64, 64), 256, 0, stream>>>(q8, part, 64, 256, 8);
    k_finalize2<<<64, 256, 0, stream>>>(part, 64, 512 * 256, g2_1, b2_1, st21);
    k_bnpackC<64, 256><<<512, 256, 0, stream>>>(q8, st21, actA);
    k_conv1x1_bp2<<<512, 256, 0, stream>>>(actA, wp22, c22);             // [512,256,16,16] i8
    k_stats_i8<<<dim3(256, 32), 256, 0, stream>>>(c22, part, 256, 256, 16);
    k_finalize2<<<256, 256, 0, stream>>>(part, 32, 512 * 256, g2_2, b2_2, st22);
    k_poolpack3<<<32768, 256, 0, stream>>>(c22, st22, spk3, npk3);       // packed 8x8

    // ---- layer 3 ----
    k_convg_bp<256, 8><<<2048, 256, 0, stream>>>(spk3, npk3, wpk31, q8); // [512,256,8,8] i8
    k_stats_i8<<<dim3(256, 32), 256, 0, stream>>>(q8, part, 256, 64, 16);
    k_finalize2<<<256, 256, 0, stream>>>(part, 32, 512 * 64, g3_1, b3_1, st31);
    k_bnpackC<256, 64><<<128, 256, 0, stream>>>(q8, st31, actA);
    k_conv1x1_bp3<<<512, 256, 0, stream>>>(actA, wp32, f3);              // [512,256,8,8] i16
    k_stats_i16<<<dim3(256, 32), 256, 0, stream>>>(f3, part, 256, 64, 16);
    k_finalize2<<<256, 256, 0, stream>>>(part, 32, 512 * 64, g3_2, b3_2, st32);

    // ---- FC (bn3_2 folded into weights) ----
    k_fcprep_w<<<640, 256, 0, stream>>>(fcw, st32, w2f);
    k_fcprep_b<<<10, 256, 0, stream>>>(fcw, st32, fcb, b2f);
    k_fc2<<<512, 256, 0, stream>>>(f3, w2f, b2f, out);
}

// Round 6
// 422.525 us; speedup vs baseline: 1.2172x; 1.2172x over previous
//
#include <hip/hip_runtime.h>

typedef unsigned int u32;

// ---------------------------------------------------------------------------
// LiBNet forward, bit-packed ternary arithmetic + integer intermediates.
// dot over taps = popc(nzA & nzW) - 2*popc((sA ^ sW) & nzA & nzW)
// nz masks preserve sign(0)=0 semantics exactly (padding AND exact zeros).
// conv1: ONE pass producing pooled max/min candidates (bn-independent) +
// per-channel stats via depth<=2 shuffle trees + LDS partials (no long
// dependency chains, no second conv pass).
// ---------------------------------------------------------------------------

static __device__ __forceinline__ float fsign(float x) {
    return (x > 0.f) ? 1.f : ((x < 0.f) ? -1.f : 0.f);
}
static __device__ __forceinline__ u32 pack4(int a, int b, int c, int d) {
    return (a & 0xff) | ((b & 0xff) << 8) | ((c & 0xff) << 16) | ((u32)(d & 0xff) << 24);
}

// --- merged weight prep: conv1 sign-f32, grouped packs, 1x1 packs ---
__global__ __launch_bounds__(256) void k_wprep(const float* __restrict__ w1, float* __restrict__ sw1f,
                                               const float* __restrict__ w2_1, u32* __restrict__ wpk21,
                                               const float* __restrict__ w3_1, u32* __restrict__ wpk31,
                                               const float* __restrict__ w2_2, u32* __restrict__ wp22,
                                               const float* __restrict__ w3_2, u32* __restrict__ wp32)
{
    int blk = blockIdx.x, tid = threadIdx.x;
    if (blk < 12) {
        int i = blk * 256 + tid;
        if (i < 3072) sw1f[i] = fsign(w1[i]);
        return;
    }
    if (blk == 12) {
        if (tid < 64) {   // grouped 4x4 weights, C=64
            const float* p = w2_1 + tid * 32;
            for (int r = 0; r < 8; ++r) {
                u32 sn = 0, nz = 0;
                for (int kw = 0; kw < 4; ++kw) {
                    float v = p[r * 4 + kw];
                    sn |= (u32)(v > 0.f) << kw;
                    nz |= (u32)(v != 0.f) << kw;
                }
                wpk21[tid * 8 + r] = sn | (nz << 8);
            }
        }
        {                 // 1x1 weights 256x64
            const float* p = w2_2 + (size_t)tid * 64;
            for (int j = 0; j < 2; ++j) {
                u32 sv = 0, nv = 0;
                for (int k = 0; k < 32; ++k) {
                    float v = p[j * 32 + k];
                    sv |= (u32)(v > 0.f) << k;
                    nv |= (u32)(v != 0.f) << k;
                }
                wp22[tid * 4 + j] = sv;
                wp22[tid * 4 + 2 + j] = nv;
            }
        }
        return;
    }
    {                     // blk == 13
        {                 // grouped 4x4 weights, C=256
            const float* p = w3_1 + tid * 32;
            for (int r = 0; r < 8; ++r) {
                u32 sn = 0, nz = 0;
                for (int kw = 0; kw < 4; ++kw) {
                    float v = p[r * 4 + kw];
                    sn |= (u32)(v > 0.f) << kw;
                    nz |= (u32)(v != 0.f) << kw;
                }
                wpk31[tid * 8 + r] = sn | (nz << 8);
            }
        }
        {                 // 1x1 weights 256x256
            const float* p = w3_2 + (size_t)tid * 256;
            for (int j = 0; j < 8; ++j) {
                u32 sv = 0, nv = 0;
                for (int k = 0; k < 32; ++k) {
                    float v = p[j * 32 + k];
                    sv |= (u32)(v > 0.f) << k;
                    nv |= (u32)(v != 0.f) << k;
                }
                wp32[tid * 16 + j] = sv;
                wp32[tid * 16 + 8 + j] = nv;
            }
        }
    }
}

// --- conv1 fused: conv + pooled max/min stores + per-channel stats ---
// Block = (image b, quarter q): rows h = q*8 .. q*8+7. Wave wv covers rows
// q*8+2wv, +1 -> pooled row oh = q*4+wv. No long shuffle chains.
__global__ __launch_bounds__(256) void k_conv1f(const float* __restrict__ x,
                                                const float* __restrict__ swf,
                                                float* __restrict__ pmax,
                                                float* __restrict__ pmin,
                                                double* __restrict__ part)
{
    __shared__ float sx[3 * 35 * 35];
    __shared__ float sacc_s[64 * 65];   // [oc][64 s4-partials], pad 65
    __shared__ float sacc_q[64 * 65];
    int b = blockIdx.x >> 2, q = blockIdx.x & 3;
    for (int i = threadIdx.x; i < 3 * 35 * 35; i += 256) sx[i] = 0.f;
    __syncthreads();
    const float* xb = x + (size_t)b * 3072;
    for (int i = threadIdx.x; i < 3072; i += 256) {
        int w = i & 31, h = (i >> 5) & 31, ic = i >> 10;
        sx[(ic * 35 + h + 1) * 35 + w + 1] = xb[i];
    }
    __syncthreads();
    int pos = q * 256 + threadIdx.x;
    int h = pos >> 5, w = pos & 31;
    int lane = threadIdx.x & 63, wv = threadIdx.x >> 6;
    int oh = q * 4 + wv;
    bool statw = ((lane & 3) == 0);
    bool owner = ((lane & 33) == 0);   // even lane, lane<32
    float in[48];
#pragma unroll
    for (int ic = 0; ic < 3; ++ic)
#pragma unroll
        for (int kh = 0; kh < 4; ++kh)
#pragma unroll
            for (int kw = 0; kw < 4; ++kw)
                in[ic * 16 + kh * 4 + kw] = sx[(ic * 35 + h + kh) * 35 + w + kw];
#pragma unroll 4
    for (int oc = 0; oc < 64; ++oc) {
        const float* wp = swf + oc * 48;   // wave-uniform -> s_load
        float a0 = 0.f, a1 = 0.f, a2 = 0.f, a3 = 0.f;
#pragma unroll
        for (int k = 0; k < 48; k += 4) {
            a0 += in[k]     * wp[k];
            a1 += in[k + 1] * wp[k + 1];
            a2 += in[k + 2] * wp[k + 2];
            a3 += in[k + 3] * wp[k + 3];
        }
        float v = (a0 + a1) + (a2 + a3);
        float p1 = __shfl_xor(v, 1);                 // horizontal neighbor
        float s2 = v + p1;
        float mx = fmaxf(v, p1), mn = fminf(v, p1);
        float sq2 = v * v + p1 * p1;
        float s4  = s2  + __shfl_xor(s2, 2);
        float sq4 = sq2 + __shfl_xor(sq2, 2);
        float mx2 = fmaxf(mx, __shfl_xor(mx, 32));   // vertical neighbor
        float mn2 = fminf(mn, __shfl_xor(mn, 32));
        if (statw) {
            int idx = oc * 65 + wv * 16 + (lane >> 2);
            sacc_s[idx] = s4;
            sacc_q[idx] = sq4;
        }
        if (owner) {
            size_t po = ((size_t)(b * 64 + oc) * 16 + oh) * 16 + (lane >> 1);
            pmax[po] = mx2;
            pmin[po] = mn2;
        }
    }
    __syncthreads();
    if (threadIdx.x < 128) {
        int oc = threadIdx.x >> 1, half = threadIdx.x & 1;
        const float* sp = (half ? sacc_q : sacc_s) + oc * 65;
        double acc = 0.0;
        for (int j = 0; j < 64; ++j) acc += (double)sp[j];
        part[((size_t)oc * 2048 + blockIdx.x) * 2 + half] = acc;
    }
}

// --- bn pick (max if scale>0 else min) + binarize + row-bitpack ---
__global__ __launch_bounds__(256) void k_bnpick(const float* __restrict__ pmax,
                                                const float* __restrict__ pmin,
                                                const float4* __restrict__ st,
                                                u32* __restrict__ spk,
                                                u32* __restrict__ npk)
{
    int bc = blockIdx.x;              // b*64 + c
    int c = bc & 63;
    int t = threadIdx.x;
    int lane = t & 63, wv = t >> 6;
    float4 s = st[c];
    float mx = pmax[(size_t)bc * 256 + t];
    float mn = pmin[(size_t)bc * 256 + t];
    float raw = (s.y > 0.f) ? mx : mn;
    float v = (raw - s.x) * s.y + s.z;
    unsigned long long bs = __ballot(v > 0.f);
    unsigned long long bn = __ballot(v != 0.f);
    int r = lane >> 4;                // row within wave (4 rows x 16 cols)
    int oh = wv * 4 + r;
    size_t base = (size_t)bc * 20;
    if ((lane & 15) == 0) {
        spk[base + 1 + oh] = (((u32)(bs >> (16 * r))) & 0xffffu) << 1;
        npk[base + 1 + oh] = (((u32)(bn >> (16 * r))) & 0xffffu) << 1;
    }
    if (t < 4) {                      // zero margin slots 0,17,18,19
        int zs = (t == 0) ? 0 : (16 + t);
        spk[base + zs] = 0; npk[base + zs] = 0;
    }
}

// --- int8 stats: exact int32 block sums -> double partials ---
__global__ __launch_bounds__(256) void k_stats_i8(const signed char* __restrict__ in,
                                                  double* __restrict__ part,
                                                  int C, int HW, int bPerChunk)
{
    int c = blockIdx.x, chunk = blockIdx.y, b0 = chunk * bPerChunk;
    int q4 = HW >> 2;
    int s = 0, sq = 0;
    for (int b = b0; b < b0 + bPerChunk; ++b) {
        const u32* p = (const u32*)(in + (size_t)(b * C + c) * HW);
        for (int i = threadIdx.x; i < q4; i += 256) {
            u32 v = p[i];
            int x0 = (int)(v << 24) >> 24, x1 = (int)(v << 16) >> 24;
            int x2 = (int)(v << 8) >> 24,  x3 = (int)v >> 24;
            s += x0 + x1 + x2 + x3;
            sq += x0 * x0 + x1 * x1 + x2 * x2 + x3 * x3;
        }
    }
    __shared__ int ss[256];
    __shared__ int sb[256];
    ss[threadIdx.x] = s; sb[threadIdx.x] = sq;
    __syncthreads();
    for (int st = 128; st > 0; st >>= 1) {
        if (threadIdx.x < st) {
            ss[threadIdx.x] += ss[threadIdx.x + st];
            sb[threadIdx.x] += sb[threadIdx.x + st];
        }
        __syncthreads();
    }
    if (threadIdx.x == 0) {
        int nch = gridDim.y;
        part[(size_t)(c * nch + chunk) * 2]     = (double)ss[0];
        part[(size_t)(c * nch + chunk) * 2 + 1] = (double)sb[0];
    }
}

// --- int16 stats ---
__global__ __launch_bounds__(256) void k_stats_i16(const short* __restrict__ in,
                                                   double* __restrict__ part,
                                                   int C, int HW, int bPerChunk)
{
    int c = blockIdx.x, chunk = blockIdx.y, b0 = chunk * bPerChunk;
    int q2 = HW >> 1;
    int s = 0, sq = 0;
    for (int b = b0; b < b0 + bPerChunk; ++b) {
        const u32* p = (const u32*)(in + (size_t)(b * C + c) * HW);
        for (int i = threadIdx.x; i < q2; i += 256) {
            u32 v = p[i];
            int x0 = (int)(v << 16) >> 16, x1 = (int)v >> 16;
            s += x0 + x1;
            sq += x0 * x0 + x1 * x1;
        }
    }
    __shared__ int ss[256];
    __shared__ int sb[256];
    ss[threadIdx.x] = s; sb[threadIdx.x] = sq;
    __syncthreads();
    for (int st = 128; st > 0; st >>= 1) {
        if (threadIdx.x < st) {
            ss[threadIdx.x] += ss[threadIdx.x + st];
            sb[threadIdx.x] += sb[threadIdx.x + st];
        }
        __syncthreads();
    }
    if (threadIdx.x == 0) {
        int nch = gridDim.y;
        part[(size_t)(c * nch + chunk) * 2]     = (double)ss[0];
        part[(size_t)(c * nch + chunk) * 2 + 1] = (double)sb[0];
    }
}

// --- finalize: block per channel; mean/var -> power-of-two shift scale ---
__global__ __launch_bounds__(256) void k_finalize2(const double* __restrict__ part,
                                                   int nch, int N,
                                                   const float* __restrict__ gamma,
                                                   const float* __restrict__ beta,
                                                   float4* __restrict__ st)
{
    int c = blockIdx.x;
    double s = 0.0, sq = 0.0;
    for (int i = threadIdx.x; i < nch; i += 256) {
        s  += part[((size_t)c * nch + i) * 2];
        sq += part[((size_t)c * nch + i) * 2 + 1];
    }
    __shared__ double ss[256];
    __shared__ double sb[256];
    ss[threadIdx.x] = s; sb[threadIdx.x] = sq;
    __syncthreads();
    for (int stp = 128; stp > 0; stp >>= 1) {
        if (threadIdx.x < stp) {
            ss[threadIdx.x] += ss[threadIdx.x + stp];
            sb[threadIdx.x] += sb[threadIdx.x + stp];
        }
        __syncthreads();
    }
    if (threadIdx.x == 0) {
        double mean = ss[0] / (double)N;
        double var = sb[0] / (double)N - mean * mean;
        float inv = gamma[c] / sqrtf((float)var + 1e-5f);
        float sh = rintf(log2f(fabsf(inv) + 1e-12f));
        sh = fminf(fmaxf(sh, -4.f), 4.f);
        float scale = copysignf(exp2f(sh), inv);
        st[c] = make_float4((float)mean, scale, beta[c], 0.f);
    }
}

// --- layer2->3 bn+pool+pack: int8 in [512,256,16,16], wave per channel ---
__global__ __launch_bounds__(256) void k_poolpack3(const signed char* __restrict__ in,
                                                   const float4* __restrict__ st,
                                                   u32* __restrict__ spk,
                                                   u32* __restrict__ npk)
{
    int wv = threadIdx.x >> 6, lane = threadIdx.x & 63;
    int bc = blockIdx.x * 4 + wv;     // b*256 + c
    int c = bc & 255;
    int oh = lane >> 3, ow = lane & 7;
    float4 s = st[c];
    const signed char* p = in + (size_t)bc * 256 + (2 * oh) * 16 + 2 * ow;
    short s01 = *(const short*)p;
    short s23 = *(const short*)(p + 16);
    int a0 = (int)(signed char)(s01 & 0xff), a1 = (int)(s01 >> 8);
    int a2 = (int)(signed char)(s23 & 0xff), a3 = (int)(s23 >> 8);
    bool pos = (s.y > 0.f);
    int raw = pos ? max(max(a0, a1), max(a2, a3)) : min(min(a0, a1), min(a2, a3));
    float v = ((float)raw - s.x) * s.y + s.z;
    unsigned long long bs = __ballot(v > 0.f);
    unsigned long long bn = __ballot(v != 0.f);
    size_t base = (size_t)bc * 12;
    if (ow == 0) {
        spk[base + 1 + oh] = (((u32)(bs >> (8 * oh))) & 0xffu) << 1;
        npk[base + 1 + oh] = (((u32)(bn >> (8 * oh))) & 0xffu) << 1;
    }
    if (lane < 4) {                   // zero margin slots 0,9,10,11
        int zs = (lane == 0) ? 0 : (8 + lane);
        spk[base + zs] = 0; npk[base + zs] = 0;
    }
}

// --- grouped 4x4 binary conv, bit-packed in, int8 out. Thread=(b,group,row). ---
template <int C, int H>
__global__ __launch_bounds__(256) void k_convg_bp(const u32* __restrict__ spk,
                                                  const u32* __restrict__ npk,
                                                  const u32* __restrict__ wpk,
                                                  signed char* __restrict__ out)
{
    constexpr int SLOTS = (H == 16) ? 20 : 12;
    int t = blockIdx.x * 256 + threadIdx.x;
    int h = t % H; int r0 = t / H;
    int g = r0 % (C / 2); int b = r0 / (C / 2);
    const u32* sp = spk + (size_t)(b * C + 2 * g) * SLOTS + h;
    const u32* np = npk + (size_t)(b * C + 2 * g) * SLOTS + h;
    u32 S[8], N[8];
#pragma unroll
    for (int jc = 0; jc < 2; ++jc)
#pragma unroll
        for (int jj = 0; jj < 4; ++jj) {    // slot h+jj = input row h-1+jj
            S[jc * 4 + jj] = sp[jc * SLOTS + jj];
            N[jc * 4 + jj] = np[jc * SLOTS + jj];
        }
    const u32* wq = wpk + (size_t)(2 * g) * 8;
    u32 Ws0[8], Wn0[8], Ws1[8], Wn1[8];
#pragma unroll
    for (int r = 0; r < 8; ++r) {
        u32 a = wq[r];      Ws0[r] = a & 15u;  Wn0[r] = (a >> 8) & 15u;
        u32 bb = wq[8 + r]; Ws1[r] = bb & 15u; Wn1[r] = (bb >> 8) & 15u;
    }
    int v0[H], v1[H];
#pragma unroll
    for (int w = 0; w < H; ++w) {
        int snz0 = 0, smis0 = 0, snz1 = 0, smis1 = 0;
#pragma unroll
        for (int r = 0; r < 8; ++r) {
            u32 ss = (S[r] >> w) & 15u;
            u32 nn = (N[r] >> w) & 15u;
            u32 nz0 = nn & Wn0[r]; u32 m0 = (ss ^ Ws0[r]) & nz0;
            snz0 += __popc(nz0); smis0 += __popc(m0);
            u32 nz1 = nn & Wn1[r]; u32 m1 = (ss ^ Ws1[r]) & nz1;
            snz1 += __popc(nz1); smis1 += __popc(m1);
        }
        v0[w] = snz0 - 2 * smis0;
        v1[w] = snz1 - 2 * smis1;
    }
    signed char* o0 = out + ((size_t)((b * C + 2 * g) * H + h)) * H;
    signed char* o1 = o0 + (size_t)H * H;
    u32 wb0[H / 4], wb1[H / 4];
#pragma unroll
    for (int j = 0; j < H / 4; ++j) {
        wb0[j] = pack4(v0[4*j], v0[4*j+1], v0[4*j+2], v0[4*j+3]);
        wb1[j] = pack4(v1[4*j], v1[4*j+1], v1[4*j+2], v1[4*j+3]);
    }
    if constexpr (H == 16) {
        *(uint4*)o0 = make_uint4(wb0[0], wb0[1], wb0[2], wb0[3]);
        *(uint4*)o1 = make_uint4(wb1[0], wb1[1], wb1[2], wb1[3]);
    } else {
        *(uint2*)o0 = make_uint2(wb0[0], wb0[1]);
        *(uint2*)o1 = make_uint2(wb1[0], wb1[1]);
    }
}

// --- bn + binarize + channel-bitpack from int8: act[t] = {signs..., nz...} ---
template <int C, int HW>
__global__ __launch_bounds__(256) void k_bnpackC(const signed char* __restrict__ q,
                                                 const float4* __restrict__ st,
                                                 u32* __restrict__ act)
{
    constexpr int W = C / 32;
    int t = blockIdx.x * 256 + threadIdx.x;   // t = b*HW + hw
    int hw = t % HW; int b = t / HW;
    const signed char* qp = q + (size_t)b * C * HW + hw;
    u32* ap = act + (size_t)t * 2 * W;
#pragma unroll
    for (int j = 0; j < W; ++j) {
        u32 sv = 0, nv = 0;
#pragma unroll
        for (int k = 0; k < 32; ++k) {
            int c = j * 32 + k;
            float4 s = st[c];
            float v = ((float)qp[(size_t)c * HW] - s.x) * s.y + s.z;
            sv |= (u32)(v > 0.f) << k;
            nv |= (u32)(v != 0.f) << k;
        }
        ap[j] = sv; ap[W + j] = nv;
    }
}

// --- 1x1 conv, Cin=64, Cout=256, HW=256, int8 out. Thread=(b,hw). ---
__global__ __launch_bounds__(256) void k_conv1x1_bp2(const u32* __restrict__ act,
                                                     const u32* __restrict__ wp,
                                                     signed char* __restrict__ out)
{
    int t = blockIdx.x * 256 + threadIdx.x;   // t = b*256 + hw
    int hw = t & 255; int b = t >> 8;
    uint4 av = ((const uint4*)act)[t];        // s0,s1,n0,n1
    signed char* op = out + (size_t)b * 256 * 256 + hw;
#pragma unroll 8
    for (int oc = 0; oc < 256; ++oc) {
        uint4 wv = ((const uint4*)wp)[oc];    // wave-uniform -> scalar loads
        u32 nz0 = av.z & wv.z, nz1 = av.w & wv.w;
        u32 m0 = (av.x ^ wv.x) & nz0, m1 = (av.y ^ wv.y) & nz1;
        int dot = __popc(nz0) + __popc(nz1) - 2 * (__popc(m0) + __popc(m1));
        op[(size_t)oc << 8] = (signed char)dot;
    }
}

// --- 1x1 conv, Cin=256, Cout=256 (4 chunks), HW=64, int16 out. ---
__global__ __launch_bounds__(256) void k_conv1x1_bp3(const u32* __restrict__ act,
                                                     const u32* __restrict__ wp,
                                                     short* __restrict__ out)
{
    int t = blockIdx.x * 256 + threadIdx.x;
    int hw = t & 63; int ch = (t >> 6) & 3; int b = t >> 8;
    const u32* ap = act + (size_t)(b * 64 + hw) * 16;
    u32 as[8], an[8];
#pragma unroll
    for (int j = 0; j < 8; ++j) { as[j] = ap[j]; an[j] = ap[8 + j]; }
    short* op = out + (size_t)b * 256 * 64 + hw;
#pragma unroll 4
    for (int oc = ch * 64; oc < ch * 64 + 64; ++oc) {
        const u32* wq = wp + oc * 16;
        int snz = 0, smis = 0;
#pragma unroll
        for (int j = 0; j < 8; ++j) {
            u32 nz = an[j] & wq[8 + j];
            u32 m = (as[j] ^ wq[j]) & nz;
            snz += __popc(nz); smis += __popc(m);
        }
        op[(size_t)oc * 64] = (short)(snz - 2 * smis);
    }
}

// --- FC prep (merged): fold bn3_2 into fc weights / bias ---
__global__ __launch_bounds__(256) void k_fcprep(const float* __restrict__ fcw,
                                                const float4* __restrict__ st,
                                                const float* __restrict__ fcb,
                                                float* __restrict__ w2,
                                                float* __restrict__ bias2)
{
    if (blockIdx.x < 640) {
        int idx = blockIdx.x * 256 + threadIdx.x;   // < 163840
        int k = idx & 16383;
        w2[idx] = fcw[idx] * st[k >> 6].y;
        return;
    }
    int n = blockIdx.x - 640;
    const float* p = fcw + (size_t)n * 16384;
    float acc = 0.f;
    for (int k = threadIdx.x; k < 16384; k += 256) {
        float4 s = st[k >> 6];
        acc += p[k] * (s.z - s.x * s.y);
    }
    __shared__ float ss[256];
    ss[threadIdx.x] = acc;
    __syncthreads();
    for (int stp = 128; stp > 0; stp >>= 1) {
        if (threadIdx.x < stp) ss[threadIdx.x] += ss[threadIdx.x + stp];
        __syncthreads();
    }
    if (threadIdx.x == 0) bias2[n] = ss[0] + fcb[n];
}

// --- FC: block per image, int16 features read once, 10 accumulators ---
__global__ __launch_bounds__(256) void k_fc2(const short* __restrict__ f,
                                             const float* __restrict__ w2,
                                             const float* __restrict__ bias2,
                                             float* __restrict__ out)
{
    int b = blockIdx.x, t = threadIdx.x;
    int lane = t & 63, wv = t >> 6;
    const u32* fp = (const u32*)(f + (size_t)b * 16384);
    float acc[10];
#pragma unroll
    for (int n = 0; n < 10; ++n) acc[n] = 0.f;
    for (int i = 0; i < 32; ++i) {
        int j = i * 256 + t;                 // u32 index; features 2j, 2j+1
        u32 v = fp[j];
        float f0 = (float)((int)(v << 16) >> 16);
        float f1 = (float)((int)v >> 16);
#pragma unroll
        for (int n = 0; n < 10; ++n) {
            float2 wv2 = *(const float2*)(w2 + (size_t)n * 16384 + 2 * j);
            acc[n] += f0 * wv2.x + f1 * wv2.y;
        }
    }
#pragma unroll
    for (int n = 0; n < 10; ++n)
#pragma unroll
        for (int m = 1; m < 64; m <<= 1) acc[n] += __shfl_xor(acc[n], m);
    __shared__ float sred[4][10];
    if (lane == 0)
#pragma unroll
        for (int n = 0; n < 10; ++n) sred[wv][n] = acc[n];
    __syncthreads();
    if (t < 10)
        out[b * 10 + t] = sred[0][t] + sred[1][t] + sred[2][t] + sred[3][t] + bias2[t];
}

extern "C" void kernel_launch(void* const* d_in, const int* in_sizes, int n_in,
                              void* d_out, int out_size, void* d_ws, size_t ws_size,
                              hipStream_t stream)
{
    const float* x    = (const float*)d_in[0];
    const float* w1   = (const float*)d_in[1];
    const float* g1   = (const float*)d_in[2];
    const float* b1   = (const float*)d_in[3];
    const float* w2_1 = (const float*)d_in[4];
    const float* g2_1 = (const float*)d_in[5];
    const float* b2_1 = (const float*)d_in[6];
    const float* w2_2 = (const float*)d_in[7];
    const float* g2_2 = (const float*)d_in[8];
    const float* b2_2 = (const float*)d_in[9];
    const float* w3_1 = (const float*)d_in[10];
    const float* g3_1 = (const float*)d_in[11];
    const float* b3_1 = (const float*)d_in[12];
    const float* w3_2 = (const float*)d_in[13];
    const float* g3_2 = (const float*)d_in[14];
    const float* b3_2 = (const float*)d_in[15];
    const float* fcw  = (const float*)d_in[16];
    const float* fcb  = (const float*)d_in[17];
    float* out = (float*)d_out;

    // workspace layout (bytes). pmax/pmin alias later c22/f3/q8 (write-after-
    // consume ordering verified in launch sequence below).
    const size_t OFF_PMAX = 0;          // 33,554,432  (-> c22 later)
    const size_t OFF_PMIN = 33554432;   // 33,554,432  (-> f3 @33.5M, q8 @50.3M)
    const size_t OFF_F3   = 33554432;   // 16,777,216  conv3_2 int16 out
    const size_t OFF_Q    = 50331648;   //  8,388,608  convg int8 outs
    const size_t OFF_SPK2 = 67108864;   //  2,621,440  [512][64][20]
    const size_t OFF_NPK2 = 69730304;   //  2,621,440
    const size_t OFF_SPK3 = 72351744;   //  6,291,456  [512][256][12]
    const size_t OFF_NPK3 = 78643200;   //  6,291,456
    const size_t OFF_A    = 84934656;   //  2,097,152  packed acts
    const size_t OFF_WPK21= 87031808;   //  2,048
    const size_t OFF_WPK31= 87033856;   //  8,192
    const size_t OFF_WP22 = 87042048;   //  4,096
    const size_t OFF_WP32 = 87046144;   //  16,384
    const size_t OFF_PART = 87062528;   //  2,097,152  (64ch x 2048 x 2 f64)
    const size_t OFF_ST   = 89159680;   //  20,480     5 x 256 float4
    const size_t OFF_SW1  = 89180160;   //  12,288     conv1 signed weights f32
    const size_t OFF_W2   = 89192448;   //  655,360    bn-folded fc weights
    const size_t OFF_B2   = 89847808;   //  256        bn-folded fc bias
    const size_t NEED     = OFF_B2 + 256;
    if (ws_size < NEED) return;

    char* ws = (char*)d_ws;
    float* pmax = (float*)(ws + OFF_PMAX);
    float* pmin = (float*)(ws + OFF_PMIN);
    signed char* c22 = (signed char*)(ws + OFF_PMAX);  // after bnpick consumes pmax
    short* f3  = (short*)(ws + OFF_F3);                // after bnpick consumes pmin
    signed char* q8 = (signed char*)(ws + OFF_Q);      // after bnpick consumes pmin
    u32* spk2  = (u32*)(ws + OFF_SPK2);
    u32* npk2  = (u32*)(ws + OFF_NPK2);
    u32* spk3  = (u32*)(ws + OFF_SPK3);
    u32* npk3  = (u32*)(ws + OFF_NPK3);
    u32* actA  = (u32*)(ws + OFF_A);
    u32* wpk21 = (u32*)(ws + OFF_WPK21);
    u32* wpk31 = (u32*)(ws + OFF_WPK31);
    u32* wp22  = (u32*)(ws + OFF_WP22);
    u32* wp32  = (u32*)(ws + OFF_WP32);
    double* part = (double*)(ws + OFF_PART);
    float4* st1  = (float4*)(ws + OFF_ST);
    float4* st21 = st1 + 256;
    float4* st22 = st21 + 256;
    float4* st31 = st22 + 256;
    float4* st32 = st31 + 256;
    float* sw1f  = (float*)(ws + OFF_SW1);
    float* w2f   = (float*)(ws + OFF_W2);
    float* b2f   = (float*)(ws + OFF_B2);

    // ---- weight prep (all binarized weights, one launch) ----
    k_wprep<<<14, 256, 0, stream>>>(w1, sw1f, w2_1, wpk21, w3_1, wpk31, w2_2, wp22, w3_2, wp32);

    // ---- layer 1: one fused conv pass ----
    k_conv1f<<<2048, 256, 0, stream>>>(x, sw1f, pmax, pmin, part);
    k_finalize2<<<64, 256, 0, stream>>>(part, 2048, 512 * 1024, g1, b1, st1);
    k_bnpick<<<32768, 256, 0, stream>>>(pmax, pmin, st1, spk2, npk2);    // packed 16x16

    // ---- layer 2 ----
    k_convg_bp<64, 16><<<1024, 256, 0, stream>>>(spk2, npk2, wpk21, q8); // [512,64,16,16] i8
    k_stats_i8<<<dim3(64, 64), 256, 0, stream>>>(q8, part, 64, 256, 8);
    k_finalize2<<<64, 256, 0, stream>>>(part, 64, 512 * 256, g2_1, b2_1, st21);
    k_bnpackC<64, 256><<<512, 256, 0, stream>>>(q8, st21, actA);
    k_conv1x1_bp2<<<512, 256, 0, stream>>>(actA, wp22, c22);             // [512,256,16,16] i8
    k_stats_i8<<<dim3(256, 32), 256, 0, stream>>>(c22, part, 256, 256, 16);
    k_finalize2<<<256, 256, 0, stream>>>(part, 32, 512 * 256, g2_2, b2_2, st22);
    k_poolpack3<<<32768, 256, 0, stream>>>(c22, st22, spk3, npk3);       // packed 8x8

    // ---- layer 3 ----
    k_convg_bp<256, 8><<<2048, 256, 0, stream>>>(spk3, npk3, wpk31, q8); // [512,256,8,8] i8
    k_stats_i8<<<dim3(256, 32), 256, 0, stream>>>(q8, part, 256, 64, 16);
    k_finalize2<<<256, 256, 0, stream>>>(part, 32, 512 * 64, g3_1, b3_1, st31);
    k_bnpackC<256, 64><<<128, 256, 0, stream>>>(q8, st31, actA);
    k_conv1x1_bp3<<<512, 256, 0, stream>>>(actA, wp32, f3);              // [512,256,8,8] i16
    k_stats_i16<<<dim3(256, 32), 256, 0, stream>>>(f3, part, 256, 64, 16);
    k_finalize2<<<256, 256, 0, stream>>>(part, 32, 512 * 64, g3_2, b3_2, st32);

    // ---- FC (bn3_2 folded into weights) ----
    k_fcprep<<<650, 256, 0, stream>>>(fcw, st32, fcb, w2f, b2f);
    k_fc2<<<512, 256, 0, stream>>>(f3, w2f, b2f, out);
}

// Round 7
// 370.078 us; speedup vs baseline: 1.3897x; 1.1417x over previous
//
#include <hip/hip_runtime.h>

typedef unsigned int u32;

// ---------------------------------------------------------------------------
// LiBNet forward, bit-packed ternary arithmetic + integer intermediates.
// dot over taps = popc(nzA & nzW) - 2*popc((sA ^ sW) & nzA & nzW)
// nz masks preserve sign(0)=0 semantics exactly (padding AND exact zeros).
// conv1: ONE pass, window held in VGPRs (launch_bounds(256,4)), pooled
// max/min candidates + per-channel stats via s8 shuffle partials.
// Grouped convs fuse their own (exact integer) bn stats.
// ---------------------------------------------------------------------------

static __device__ __forceinline__ float fsign(float x) {
    return (x > 0.f) ? 1.f : ((x < 0.f) ? -1.f : 0.f);
}
static __device__ __forceinline__ u32 pack4(int a, int b, int c, int d) {
    return (a & 0xff) | ((b & 0xff) << 8) | ((c & 0xff) << 16) | ((u32)(d & 0xff) << 24);
}

// --- merged weight prep: conv1 sign-f32, grouped packs, 1x1 packs ---
__global__ __launch_bounds__(256) void k_wprep(const float* __restrict__ w1, float* __restrict__ sw1f,
                                               const float* __restrict__ w2_1, u32* __restrict__ wpk21,
                                               const float* __restrict__ w3_1, u32* __restrict__ wpk31,
                                               const float* __restrict__ w2_2, u32* __restrict__ wp22,
                                               const float* __restrict__ w3_2, u32* __restrict__ wp32)
{
    int blk = blockIdx.x, tid = threadIdx.x;
    if (blk < 12) {
        int i = blk * 256 + tid;
        if (i < 3072) sw1f[i] = fsign(w1[i]);
        return;
    }
    if (blk == 12) {
        if (tid < 64) {   // grouped 4x4 weights, C=64
            const float* p = w2_1 + tid * 32;
            for (int r = 0; r < 8; ++r) {
                u32 sn = 0, nz = 0;
                for (int kw = 0; kw < 4; ++kw) {
                    float v = p[r * 4 + kw];
                    sn |= (u32)(v > 0.f) << kw;
                    nz |= (u32)(v != 0.f) << kw;
                }
                wpk21[tid * 8 + r] = sn | (nz << 8);
            }
        }
        {                 // 1x1 weights 256x64
            const float* p = w2_2 + (size_t)tid * 64;
            for (int j = 0; j < 2; ++j) {
                u32 sv = 0, nv = 0;
                for (int k = 0; k < 32; ++k) {
                    float v = p[j * 32 + k];
                    sv |= (u32)(v > 0.f) << k;
                    nv |= (u32)(v != 0.f) << k;
                }
                wp22[tid * 4 + j] = sv;
                wp22[tid * 4 + 2 + j] = nv;
            }
        }
        return;
    }
    {                     // blk == 13
        {                 // grouped 4x4 weights, C=256
            const float* p = w3_1 + tid * 32;
            for (int r = 0; r < 8; ++r) {
                u32 sn = 0, nz = 0;
                for (int kw = 0; kw < 4; ++kw) {
                    float v = p[r * 4 + kw];
                    sn |= (u32)(v > 0.f) << kw;
                    nz |= (u32)(v != 0.f) << kw;
                }
                wpk31[tid * 8 + r] = sn | (nz << 8);
            }
        }
        {                 // 1x1 weights 256x256
            const float* p = w3_2 + (size_t)tid * 256;
            for (int j = 0; j < 8; ++j) {
                u32 sv = 0, nv = 0;
                for (int k = 0; k < 32; ++k) {
                    float v = p[j * 32 + k];
                    sv |= (u32)(v > 0.f) << k;
                    nv |= (u32)(v != 0.f) << k;
                }
                wp32[tid * 16 + j] = sv;
                wp32[tid * 16 + 8 + j] = nv;
            }
        }
    }
}

// --- conv1 fused: conv + pooled max/min stores + per-channel stats ---
// launch_bounds(256,4): 128-VGPR budget keeps the 48-tap window resident.
__global__ __launch_bounds__(256, 4) void k_conv1f(const float* __restrict__ x,
                                                   const float* __restrict__ swf,
                                                   float* __restrict__ pmax,
                                                   float* __restrict__ pmin,
                                                   double* __restrict__ part)
{
    __shared__ float sx[3 * 35 * 35];
    __shared__ float sacc_s[64 * 33];   // [oc][32 s8-partials], pad 33
    __shared__ float sacc_q[64 * 33];
    int b = blockIdx.x >> 2, q = blockIdx.x & 3;
    for (int i = threadIdx.x; i < 3 * 35 * 35; i += 256) sx[i] = 0.f;
    __syncthreads();
    const float* xb = x + (size_t)b * 3072;
    for (int i = threadIdx.x; i < 3072; i += 256) {
        int w = i & 31, h = (i >> 5) & 31, ic = i >> 10;
        sx[(ic * 35 + h + 1) * 35 + w + 1] = xb[i];
    }
    __syncthreads();
    int pos = q * 256 + threadIdx.x;
    int h = pos >> 5, w = pos & 31;
    int lane = threadIdx.x & 63, wv = threadIdx.x >> 6;
    int oh = q * 4 + wv;
    bool statw = ((lane & 7) == 0);
    bool owner = ((lane & 33) == 0);   // even lane, lane<32
    float in[48];
#pragma unroll
    for (int ic = 0; ic < 3; ++ic)
#pragma unroll
        for (int kh = 0; kh < 4; ++kh)
#pragma unroll
            for (int kw = 0; kw < 4; ++kw)
                in[ic * 16 + kh * 4 + kw] = sx[(ic * 35 + h + kh) * 35 + w + kw];
    float* pmaxb = pmax + ((size_t)(b * 64) * 16 + oh) * 16 + (lane >> 1);
    float* pminb = pmin + ((size_t)(b * 64) * 16 + oh) * 16 + (lane >> 1);
#pragma unroll 8
    for (int oc = 0; oc < 64; ++oc) {
        const float* wp = swf + oc * 48;   // wave-uniform -> s_load
        float a0 = 0.f, a1 = 0.f, a2 = 0.f, a3 = 0.f;
#pragma unroll
        for (int k = 0; k < 48; k += 4) {
            a0 += in[k]     * wp[k];
            a1 += in[k + 1] * wp[k + 1];
            a2 += in[k + 2] * wp[k + 2];
            a3 += in[k + 3] * wp[k + 3];
        }
        float v = (a0 + a1) + (a2 + a3);
        float p1 = __shfl_xor(v, 1);                 // horizontal neighbor
        float s2 = v + p1;
        float sq2 = v * v + p1 * p1;
        float mx = fmaxf(v, p1), mn = fminf(v, p1);
        float s4  = s2  + __shfl_xor(s2, 2);
        float sq4 = sq2 + __shfl_xor(sq2, 2);
        float s8  = s4  + __shfl_xor(s4, 4);
        float sq8 = sq4 + __shfl_xor(sq4, 4);
        float mx2 = fmaxf(mx, __shfl_xor(mx, 32));   // vertical neighbor
        float mn2 = fminf(mn, __shfl_xor(mn, 32));
        if (statw) {
            int idx = oc * 33 + wv * 8 + (lane >> 3);
            sacc_s[idx] = s8;
            sacc_q[idx] = sq8;
        }
        if (owner) {
            pmaxb[oc * 256] = mx2;
            pminb[oc * 256] = mn2;
        }
    }
    __syncthreads();
    if (threadIdx.x < 128) {
        int oc = threadIdx.x >> 1, half = threadIdx.x & 1;
        const float* sp = (half ? sacc_q : sacc_s) + oc * 33;
        double acc = 0.0;
        for (int j = 0; j < 32; ++j) acc += (double)sp[j];
        part[((size_t)oc * 2048 + blockIdx.x) * 2 + half] = acc;
    }
}

// --- bn pick (max if scale>0 else min) + binarize + row-bitpack ---
__global__ __launch_bounds__(256) void k_bnpick(const float* __restrict__ pmax,
                                                const float* __restrict__ pmin,
                                                const float4* __restrict__ st,
                                                u32* __restrict__ spk,
                                                u32* __restrict__ npk)
{
    int bc = blockIdx.x;              // b*64 + c
    int c = bc & 63;
    int t = threadIdx.x;
    int lane = t & 63, wv = t >> 6;
    float4 s = st[c];
    float mx = pmax[(size_t)bc * 256 + t];
    float mn = pmin[(size_t)bc * 256 + t];
    float raw = (s.y > 0.f) ? mx : mn;
    float v = (raw - s.x) * s.y + s.z;
    unsigned long long bs = __ballot(v > 0.f);
    unsigned long long bn = __ballot(v != 0.f);
    int r = lane >> 4;                // row within wave (4 rows x 16 cols)
    int oh = wv * 4 + r;
    size_t base = (size_t)bc * 20;
    if ((lane & 15) == 0) {
        spk[base + 1 + oh] = (((u32)(bs >> (16 * r))) & 0xffffu) << 1;
        npk[base + 1 + oh] = (((u32)(bn >> (16 * r))) & 0xffffu) << 1;
    }
    if (t < 4) {                      // zero margin slots 0,17,18,19
        int zs = (t == 0) ? 0 : (16 + t);
        spk[base + zs] = 0; npk[base + zs] = 0;
    }
}

// --- int8 stats: exact int32 block sums -> double partials ---
__global__ __launch_bounds__(256) void k_stats_i8(const signed char* __restrict__ in,
                                                  double* __restrict__ part,
                                                  int C, int HW, int bPerChunk)
{
    int c = blockIdx.x, chunk = blockIdx.y, b0 = chunk * bPerChunk;
    int q4 = HW >> 2;
    int s = 0, sq = 0;
    for (int b = b0; b < b0 + bPerChunk; ++b) {
        const u32* p = (const u32*)(in + (size_t)(b * C + c) * HW);
        for (int i = threadIdx.x; i < q4; i += 256) {
            u32 v = p[i];
            int x0 = (int)(v << 24) >> 24, x1 = (int)(v << 16) >> 24;
            int x2 = (int)(v << 8) >> 24,  x3 = (int)v >> 24;
            s += x0 + x1 + x2 + x3;
            sq += x0 * x0 + x1 * x1 + x2 * x2 + x3 * x3;
        }
    }
    __shared__ int ss[256];
    __shared__ int sb[256];
    ss[threadIdx.x] = s; sb[threadIdx.x] = sq;
    __syncthreads();
    for (int st = 128; st > 0; st >>= 1) {
        if (threadIdx.x < st) {
            ss[threadIdx.x] += ss[threadIdx.x + st];
            sb[threadIdx.x] += sb[threadIdx.x + st];
        }
        __syncthreads();
    }
    if (threadIdx.x == 0) {
        int nch = gridDim.y;
        part[(size_t)(c * nch + chunk) * 2]     = (double)ss[0];
        part[(size_t)(c * nch + chunk) * 2 + 1] = (double)sb[0];
    }
}

// --- int16 stats ---
__global__ __launch_bounds__(256) void k_stats_i16(const short* __restrict__ in,
                                                   double* __restrict__ part,
                                                   int C, int HW, int bPerChunk)
{
    int c = blockIdx.x, chunk = blockIdx.y, b0 = chunk * bPerChunk;
    int q2 = HW >> 1;
    int s = 0, sq = 0;
    for (int b = b0; b < b0 + bPerChunk; ++b) {
        const u32* p = (const u32*)(in + (size_t)(b * C + c) * HW);
        for (int i = threadIdx.x; i < q2; i += 256) {
            u32 v = p[i];
            int x0 = (int)(v << 16) >> 16, x1 = (int)v >> 16;
            s += x0 + x1;
            sq += x0 * x0 + x1 * x1;
        }
    }
    __shared__ int ss[256];
    __shared__ int sb[256];
    ss[threadIdx.x] = s; sb[threadIdx.x] = sq;
    __syncthreads();
    for (int st = 128; st > 0; st >>= 1) {
        if (threadIdx.x < st) {
            ss[threadIdx.x] += ss[threadIdx.x + st];
            sb[threadIdx.x] += sb[threadIdx.x + st];
        }
        __syncthreads();
    }
    if (threadIdx.x == 0) {
        int nch = gridDim.y;
        part[(size_t)(c * nch + chunk) * 2]     = (double)ss[0];
        part[(size_t)(c * nch + chunk) * 2 + 1] = (double)sb[0];
    }
}

// --- finalize: block per channel; mean/var -> power-of-two shift scale ---
__global__ __launch_bounds__(256) void k_finalize2(const double* __restrict__ part,
                                                   int nch, int N,
                                                   const float* __restrict__ gamma,
                                                   const float* __restrict__ beta,
                                                   float4* __restrict__ st)
{
    int c = blockIdx.x;
    double s = 0.0, sq = 0.0;
    for (int i = threadIdx.x; i < nch; i += 256) {
        s  += part[((size_t)c * nch + i) * 2];
        sq += part[((size_t)c * nch + i) * 2 + 1];
    }
    __shared__ double ss[256];
    __shared__ double sb[256];
    ss[threadIdx.x] = s; sb[threadIdx.x] = sq;
    __syncthreads();
    for (int stp = 128; stp > 0; stp >>= 1) {
        if (threadIdx.x < stp) {
            ss[threadIdx.x] += ss[threadIdx.x + stp];
            sb[threadIdx.x] += sb[threadIdx.x + stp];
        }
        __syncthreads();
    }
    if (threadIdx.x == 0) {
        double mean = ss[0] / (double)N;
        double var = sb[0] / (double)N - mean * mean;
        float inv = gamma[c] / sqrtf((float)var + 1e-5f);
        float sh = rintf(log2f(fabsf(inv) + 1e-12f));
        sh = fminf(fmaxf(sh, -4.f), 4.f);
        float scale = copysignf(exp2f(sh), inv);
        st[c] = make_float4((float)mean, scale, beta[c], 0.f);
    }
}

// --- layer2->3 bn+pool+pack: int8 in [512,256,16,16], wave per channel ---
__global__ __launch_bounds__(256) void k_poolpack3(const signed char* __restrict__ in,
                                                   const float4* __restrict__ st,
                                                   u32* __restrict__ spk,
                                                   u32* __restrict__ npk)
{
    int wv = threadIdx.x >> 6, lane = threadIdx.x & 63;
    int bc = blockIdx.x * 4 + wv;     // b*256 + c
    int c = bc & 255;
    int oh = lane >> 3, ow = lane & 7;
    float4 s = st[c];
    const signed char* p = in + (size_t)bc * 256 + (2 * oh) * 16 + 2 * ow;
    short s01 = *(const short*)p;
    short s23 = *(const short*)(p + 16);
    int a0 = (int)(signed char)(s01 & 0xff), a1 = (int)(s01 >> 8);
    int a2 = (int)(signed char)(s23 & 0xff), a3 = (int)(s23 >> 8);
    bool pos = (s.y > 0.f);
    int raw = pos ? max(max(a0, a1), max(a2, a3)) : min(min(a0, a1), min(a2, a3));
    float v = ((float)raw - s.x) * s.y + s.z;
    unsigned long long bs = __ballot(v > 0.f);
    unsigned long long bn = __ballot(v != 0.f);
    size_t base = (size_t)bc * 12;
    if (ow == 0) {
        spk[base + 1 + oh] = (((u32)(bs >> (8 * oh))) & 0xffu) << 1;
        npk[base + 1 + oh] = (((u32)(bn >> (8 * oh))) & 0xffu) << 1;
    }
    if (lane < 4) {                   // zero margin slots 0,9,10,11
        int zs = (lane == 0) ? 0 : (8 + lane);
        spk[base + zs] = 0; npk[base + zs] = 0;
    }
}

// --- grouped 4x4 binary conv, bit-packed in, int8 out, FUSED bn stats. ---
// Thread=(b,group,row). Stats: exact int sums reduced over the H-lane group.
template <int C, int H>
__global__ __launch_bounds__(256) void k_convg_bp(const u32* __restrict__ spk,
                                                  const u32* __restrict__ npk,
                                                  const u32* __restrict__ wpk,
                                                  signed char* __restrict__ out,
                                                  double* __restrict__ part)
{
    constexpr int SLOTS = (H == 16) ? 20 : 12;
    int t = blockIdx.x * 256 + threadIdx.x;
    int h = t % H; int r0 = t / H;
    int g = r0 % (C / 2); int b = r0 / (C / 2);
    int lane = threadIdx.x & 63;
    const u32* sp = spk + (size_t)(b * C + 2 * g) * SLOTS + h;
    const u32* np = npk + (size_t)(b * C + 2 * g) * SLOTS + h;
    u32 S[8], N[8];
#pragma unroll
    for (int jc = 0; jc < 2; ++jc)
#pragma unroll
        for (int jj = 0; jj < 4; ++jj) {    // slot h+jj = input row h-1+jj
            S[jc * 4 + jj] = sp[jc * SLOTS + jj];
            N[jc * 4 + jj] = np[jc * SLOTS + jj];
        }
    const u32* wq = wpk + (size_t)(2 * g) * 8;
    u32 Ws0[8], Wn0[8], Ws1[8], Wn1[8];
#pragma unroll
    for (int r = 0; r < 8; ++r) {
        u32 a = wq[r];      Ws0[r] = a & 15u;  Wn0[r] = (a >> 8) & 15u;
        u32 bb = wq[8 + r]; Ws1[r] = bb & 15u; Wn1[r] = (bb >> 8) & 15u;
    }
    int v0[H], v1[H];
    int s0 = 0, q0 = 0, s1 = 0, q1 = 0;
#pragma unroll
    for (int w = 0; w < H; ++w) {
        int snz0 = 0, smis0 = 0, snz1 = 0, smis1 = 0;
#pragma unroll
        for (int r = 0; r < 8; ++r) {
            u32 ss = (S[r] >> w) & 15u;
            u32 nn = (N[r] >> w) & 15u;
            u32 nz0 = nn & Wn0[r]; u32 m0 = (ss ^ Ws0[r]) & nz0;
            snz0 += __popc(nz0); smis0 += __popc(m0);
            u32 nz1 = nn & Wn1[r]; u32 m1 = (ss ^ Ws1[r]) & nz1;
            snz1 += __popc(nz1); smis1 += __popc(m1);
        }
        v0[w] = snz0 - 2 * smis0;
        v1[w] = snz1 - 2 * smis1;
        s0 += v0[w]; q0 += v0[w] * v0[w];
        s1 += v1[w]; q1 += v1[w] * v1[w];
    }
    // group-of-H lanes (aligned) hold one (b, g): butterfly int reduce
#pragma unroll
    for (int m = 1; m < H; m <<= 1) {
        s0 += __shfl_xor(s0, m); q0 += __shfl_xor(q0, m);
        s1 += __shfl_xor(s1, m); q1 += __shfl_xor(q1, m);
    }
    if ((lane & (H - 1)) == 0) {
        part[((size_t)(2 * g) * 512 + b) * 2]         = (double)s0;
        part[((size_t)(2 * g) * 512 + b) * 2 + 1]     = (double)q0;
        part[((size_t)(2 * g + 1) * 512 + b) * 2]     = (double)s1;
        part[((size_t)(2 * g + 1) * 512 + b) * 2 + 1] = (double)q1;
    }
    signed char* o0 = out + ((size_t)((b * C + 2 * g) * H + h)) * H;
    signed char* o1 = o0 + (size_t)H * H;
    u32 wb0[H / 4], wb1[H / 4];
#pragma unroll
    for (int j = 0; j < H / 4; ++j) {
        wb0[j] = pack4(v0[4*j], v0[4*j+1], v0[4*j+2], v0[4*j+3]);
        wb1[j] = pack4(v1[4*j], v1[4*j+1], v1[4*j+2], v1[4*j+3]);
    }
    if constexpr (H == 16) {
        *(uint4*)o0 = make_uint4(wb0[0], wb0[1], wb0[2], wb0[3]);
        *(uint4*)o1 = make_uint4(wb1[0], wb1[1], wb1[2], wb1[3]);
    } else {
        *(uint2*)o0 = make_uint2(wb0[0], wb0[1]);
        *(uint2*)o1 = make_uint2(wb1[0], wb1[1]);
    }
}

// --- bn + binarize + channel-bitpack from int8: act[t] = {signs..., nz...} ---
template <int C, int HW>
__global__ __launch_bounds__(256) void k_bnpackC(const signed char* __restrict__ q,
                                                 const float4* __restrict__ st,
                                                 u32* __restrict__ act)
{
    constexpr int W = C / 32;
    int t = blockIdx.x * 256 + threadIdx.x;   // t = b*HW + hw
    int hw = t % HW; int b = t / HW;
    const signed char* qp = q + (size_t)b * C * HW + hw;
    u32* ap = act + (size_t)t * 2 * W;
#pragma unroll
    for (int j = 0; j < W; ++j) {
        u32 sv = 0, nv = 0;
#pragma unroll
        for (int k = 0; k < 32; ++k) {
            int c = j * 32 + k;
            float4 s = st[c];
            float v = ((float)qp[(size_t)c * HW] - s.x) * s.y + s.z;
            sv |= (u32)(v > 0.f) << k;
            nv |= (u32)(v != 0.f) << k;
        }
        ap[j] = sv; ap[W + j] = nv;
    }
}

// --- 1x1 conv, Cin=64, Cout=256, HW=256, int8 out. Thread=(b,hw). ---
__global__ __launch_bounds__(256) void k_conv1x1_bp2(const u32* __restrict__ act,
                                                     const u32* __restrict__ wp,
                                                     signed char* __restrict__ out)
{
    int t = blockIdx.x * 256 + threadIdx.x;   // t = b*256 + hw
    int hw = t & 255; int b = t >> 8;
    uint4 av = ((const uint4*)act)[t];        // s0,s1,n0,n1
    signed char* op = out + (size_t)b * 256 * 256 + hw;
#pragma unroll 8
    for (int oc = 0; oc < 256; ++oc) {
        uint4 wv = ((const uint4*)wp)[oc];    // wave-uniform -> scalar loads
        u32 nz0 = av.z & wv.z, nz1 = av.w & wv.w;
        u32 m0 = (av.x ^ wv.x) & nz0, m1 = (av.y ^ wv.y) & nz1;
        int dot = __popc(nz0) + __popc(nz1) - 2 * (__popc(m0) + __popc(m1));
        op[(size_t)oc << 8] = (signed char)dot;
    }
}

// --- 1x1 conv, Cin=256, Cout=256 (4 chunks), HW=64, int16 out. ---
__global__ __launch_bounds__(256) void k_conv1x1_bp3(const u32* __restrict__ act,
                                                     const u32* __restrict__ wp,
                                                     short* __restrict__ out)
{
    int t = blockIdx.x * 256 + threadIdx.x;
    int hw = t & 63; int ch = (t >> 6) & 3; int b = t >> 8;
    const u32* ap = act + (size_t)(b * 64 + hw) * 16;
    u32 as[8], an[8];
#pragma unroll
    for (int j = 0; j < 8; ++j) { as[j] = ap[j]; an[j] = ap[8 + j]; }
    short* op = out + (size_t)b * 256 * 64 + hw;
#pragma unroll 4
    for (int oc = ch * 64; oc < ch * 64 + 64; ++oc) {
        const u32* wq = wp + oc * 16;
        int snz = 0, smis = 0;
#pragma unroll
        for (int j = 0; j < 8; ++j) {
            u32 nz = an[j] & wq[8 + j];
            u32 m = (as[j] ^ wq[j]) & nz;
            snz += __popc(nz); smis += __popc(m);
        }
        op[(size_t)oc * 64] = (short)(snz - 2 * smis);
    }
}

// --- FC prep (merged): fold bn3_2 into fc weights / bias ---
__global__ __launch_bounds__(256) void k_fcprep(const float* __restrict__ fcw,
                                                const float4* __restrict__ st,
                                                const float* __restrict__ fcb,
                                                float* __restrict__ w2,
                                                float* __restrict__ bias2)
{
    if (blockIdx.x < 640) {
        int idx = blockIdx.x * 256 + threadIdx.x;   // < 163840
        int k = idx & 16383;
        w2[idx] = fcw[idx] * st[k >> 6].y;
        return;
    }
    int n = blockIdx.x - 640;
    const float* p = fcw + (size_t)n * 16384;
    float acc = 0.f;
    for (int k = threadIdx.x; k < 16384; k += 256) {
        float4 s = st[k >> 6];
        acc += p[k] * (s.z - s.x * s.y);
    }
    __shared__ float ss[256];
    ss[threadIdx.x] = acc;
    __syncthreads();
    for (int stp = 128; stp > 0; stp >>= 1) {
        if (threadIdx.x < stp) ss[threadIdx.x] += ss[threadIdx.x + stp];
        __syncthreads();
    }
    if (threadIdx.x == 0) bias2[n] = ss[0] + fcb[n];
}

// --- FC: block per image, int16 features read once, 10 accumulators ---
__global__ __launch_bounds__(256) void k_fc2(const short* __restrict__ f,
                                             const float* __restrict__ w2,
                                             const float* __restrict__ bias2,
                                             float* __restrict__ out)
{
    int b = blockIdx.x, t = threadIdx.x;
    int lane = t & 63, wv = t >> 6;
    const u32* fp = (const u32*)(f + (size_t)b * 16384);
    float acc[10];
#pragma unroll
    for (int n = 0; n < 10; ++n) acc[n] = 0.f;
    for (int i = 0; i < 32; ++i) {
        int j = i * 256 + t;                 // u32 index; features 2j, 2j+1
        u32 v = fp[j];
        float f0 = (float)((int)(v << 16) >> 16);
        float f1 = (float)((int)v >> 16);
#pragma unroll
        for (int n = 0; n < 10; ++n) {
            float2 wv2 = *(const float2*)(w2 + (size_t)n * 16384 + 2 * j);
            acc[n] += f0 * wv2.x + f1 * wv2.y;
        }
    }
#pragma unroll
    for (int n = 0; n < 10; ++n)
#pragma unroll
        for (int m = 1; m < 64; m <<= 1) acc[n] += __shfl_xor(acc[n], m);
    __shared__ float sred[4][10];
    if (lane == 0)
#pragma unroll
        for (int n = 0; n < 10; ++n) sred[wv][n] = acc[n];
    __syncthreads();
    if (t < 10)
        out[b * 10 + t] = sred[0][t] + sred[1][t] + sred[2][t] + sred[3][t] + bias2[t];
}

extern "C" void kernel_launch(void* const* d_in, const int* in_sizes, int n_in,
                              void* d_out, int out_size, void* d_ws, size_t ws_size,
                              hipStream_t stream)
{
    const float* x    = (const float*)d_in[0];
    const float* w1   = (const float*)d_in[1];
    const float* g1   = (const float*)d_in[2];
    const float* b1   = (const float*)d_in[3];
    const float* w2_1 = (const float*)d_in[4];
    const float* g2_1 = (const float*)d_in[5];
    const float* b2_1 = (const float*)d_in[6];
    const float* w2_2 = (const float*)d_in[7];
    const float* g2_2 = (const float*)d_in[8];
    const float* b2_2 = (const float*)d_in[9];
    const float* w3_1 = (const float*)d_in[10];
    const float* g3_1 = (const float*)d_in[11];
    const float* b3_1 = (const float*)d_in[12];
    const float* w3_2 = (const float*)d_in[13];
    const float* g3_2 = (const float*)d_in[14];
    const float* b3_2 = (const float*)d_in[15];
    const float* fcw  = (const float*)d_in[16];
    const float* fcb  = (const float*)d_in[17];
    float* out = (float*)d_out;

    // workspace layout (bytes). pmax/pmin alias later c22/f3/q8 (write-after-
    // consume ordering verified in launch sequence below).
    const size_t OFF_PMAX = 0;          // 33,554,432  (-> c22 later)
    const size_t OFF_PMIN = 33554432;   // 33,554,432  (-> f3 @33.5M, q8 @50.3M)
    const size_t OFF_F3   = 33554432;   // 16,777,216  conv3_2 int16 out
    const size_t OFF_Q    = 50331648;   //  8,388,608  convg int8 outs
    const size_t OFF_SPK2 = 67108864;   //  2,621,440  [512][64][20]
    const size_t OFF_NPK2 = 69730304;   //  2,621,440
    const size_t OFF_SPK3 = 72351744;   //  6,291,456  [512][256][12]
    const size_t OFF_NPK3 = 78643200;   //  6,291,456
    const size_t OFF_A    = 84934656;   //  2,097,152  packed acts
    const size_t OFF_WPK21= 87031808;   //  2,048
    const size_t OFF_WPK31= 87033856;   //  8,192
    const size_t OFF_WP22 = 87042048;   //  4,096
    const size_t OFF_WP32 = 87046144;   //  16,384
    const size_t OFF_PART = 87062528;   //  2,097,152  (max 256ch x 512 x 2 f64)
    const size_t OFF_ST   = 89159680;   //  20,480     5 x 256 float4
    const size_t OFF_SW1  = 89180160;   //  12,288     conv1 signed weights f32
    const size_t OFF_W2   = 89192448;   //  655,360    bn-folded fc weights
    const size_t OFF_B2   = 89847808;   //  256        bn-folded fc bias
    const size_t NEED     = OFF_B2 + 256;
    if (ws_size < NEED) return;

    char* ws = (char*)d_ws;
    float* pmax = (float*)(ws + OFF_PMAX);
    float* pmin = (float*)(ws + OFF_PMIN);
    signed char* c22 = (signed char*)(ws + OFF_PMAX);  // after bnpick consumes pmax
    short* f3  = (short*)(ws + OFF_F3);                // after bnpick consumes pmin
    signed char* q8 = (signed char*)(ws + OFF_Q);      // after bnpick consumes pmin
    u32* spk2  = (u32*)(ws + OFF_SPK2);
    u32* npk2  = (u32*)(ws + OFF_NPK2);
    u32* spk3  = (u32*)(ws + OFF_SPK3);
    u32* npk3  = (u32*)(ws + OFF_NPK3);
    u32* actA  = (u32*)(ws + OFF_A);
    u32* wpk21 = (u32*)(ws + OFF_WPK21);
    u32* wpk31 = (u32*)(ws + OFF_WPK31);
    u32* wp22  = (u32*)(ws + OFF_WP22);
    u32* wp32  = (u32*)(ws + OFF_WP32);
    double* part = (double*)(ws + OFF_PART);
    float4* st1  = (float4*)(ws + OFF_ST);
    float4* st21 = st1 + 256;
    float4* st22 = st21 + 256;
    float4* st31 = st22 + 256;
    float4* st32 = st31 + 256;
    float* sw1f  = (float*)(ws + OFF_SW1);
    float* w2f   = (float*)(ws + OFF_W2);
    float* b2f   = (float*)(ws + OFF_B2);

    // ---- weight prep (all binarized weights, one launch) ----
    k_wprep<<<14, 256, 0, stream>>>(w1, sw1f, w2_1, wpk21, w3_1, wpk31, w2_2, wp22, w3_2, wp32);

    // ---- layer 1: one fused conv pass ----
    k_conv1f<<<2048, 256, 0, stream>>>(x, sw1f, pmax, pmin, part);
    k_finalize2<<<64, 256, 0, stream>>>(part, 2048, 512 * 1024, g1, b1, st1);
    k_bnpick<<<32768, 256, 0, stream>>>(pmax, pmin, st1, spk2, npk2);    // packed 16x16

    // ---- layer 2 ----
    k_convg_bp<64, 16><<<1024, 256, 0, stream>>>(spk2, npk2, wpk21, q8, part);
    k_finalize2<<<64, 256, 0, stream>>>(part, 512, 512 * 256, g2_1, b2_1, st21);
    k_bnpackC<64, 256><<<512, 256, 0, stream>>>(q8, st21, actA);
    k_conv1x1_bp2<<<512, 256, 0, stream>>>(actA, wp22, c22);             // [512,256,16,16] i8
    k_stats_i8<<<dim3(256, 32), 256, 0, stream>>>(c22, part, 256, 256, 16);
    k_finalize2<<<256, 256, 0, stream>>>(part, 32, 512 * 256, g2_2, b2_2, st22);
    k_poolpack3<<<32768, 256, 0, stream>>>(c22, st22, spk3, npk3);       // packed 8x8

    // ---- layer 3 ----
    k_convg_bp<256, 8><<<2048, 256, 0, stream>>>(spk3, npk3, wpk31, q8, part);
    k_finalize2<<<256, 256, 0, stream>>>(part, 512, 512 * 64, g3_1, b3_1, st31);
    k_bnpackC<256, 64><<<128, 256, 0, stream>>>(q8, st31, actA);
    k_conv1x1_bp3<<<512, 256, 0, stream>>>(actA, wp32, f3);              // [512,256,8,8] i16
    k_stats_i16<<<dim3(256, 32), 256, 0, stream>>>(f3, part, 256, 64, 16);
    k_finalize2<<<256, 256, 0, stream>>>(part, 32, 512 * 64, g3_2, b3_2, st32);

    // ---- FC (bn3_2 folded into weights) ----
    k_fcprep<<<650, 256, 0, stream>>>(fcw, st32, fcb, w2f, b2f);
    k_fc2<<<512, 256, 0, stream>>>(f3, w2f, b2f, out);
}